// Round 5
// baseline (96.154 us; speedup 1.0000x reference)
//
#include <hip/hip_runtime.h>

#define NNODES 1024
#define NHEADS 8
#define NHID 16
#define DIM 128            // NHEADS * NHID
#define NEG_SLOPE 0.2f

// K1: g = h @ W^T ; src[i,h] = g[i,h,:]·a_src ; dst[i,h] = g[i,h,:]·a_dst
__global__ __launch_bounds__(128) void proj_kernel(
    const float* __restrict__ h, const float* __restrict__ W,
    const float* __restrict__ attn_w,
    float* __restrict__ g, float* __restrict__ srcv, float* __restrict__ dstv)
{
    const int i = blockIdx.x;
    const int o = threadIdx.x;
    __shared__ float hs[DIM];
    hs[o] = h[(size_t)i * DIM + o];
    __syncthreads();
    const float4* hv = (const float4*)hs;
    const float4* wv = (const float4*)(W + (size_t)o * DIM);
    float acc = 0.f;
#pragma unroll
    for (int k = 0; k < DIM / 4; k++) {
        float4 a = hv[k]; float4 b = wv[k];
        acc = fmaf(a.x, b.x, fmaf(a.y, b.y, fmaf(a.z, b.z, fmaf(a.w, b.w, acc))));
    }
    g[(size_t)i * DIM + o] = acc;
    const int f  = o & (NHID - 1);
    const int hd = o >> 4;
    float sv = acc * attn_w[f];
    float dv = acc * attn_w[NHID + f];
#pragma unroll
    for (int off = 8; off > 0; off >>= 1) {
        sv += __shfl_xor(sv, off, 64);
        dv += __shfl_xor(dv, off, 64);
    }
    if (f == 0) { srcv[i * NHEADS + hd] = sv; dstv[i * NHEADS + hd] = dv; }
}

// K2: one block per 2 rows. ev row in LDS, in-block denominators, register-private
// weights, register accumulation with explicit 1-ahead prefetch, shuffle epilogue.
__global__ __launch_bounds__(256, 2) void fused_kernel(
    const int* __restrict__ adj, const float* __restrict__ s,
    const float* __restrict__ g, const float* __restrict__ srcv,
    const float* __restrict__ dstv, float* __restrict__ out)
{
    const int i0   = blockIdx.x * 2;
    const int tid  = threadIdx.x;
    const int h    = tid & 7;
    const int js   = tid >> 3;        // 0..31
    const int lane = tid & 63;
    const int wv   = tid >> 6;        // wave 0..3

    __shared__ float evL[2][NNODES];          // 8 KB: exp(s) or 0 per row
    __shared__ float zeA[4][NHEADS][2];
    __shared__ float zsA[4][2];
    __shared__ float statE[2][NHEADS];
    __shared__ float statS[2];
    __shared__ float redO[4][2][NHEADS][16];  // 4 KB
    __shared__ float ztA[4][2][NHEADS];

    // ---- Phase A1: ev = adj ? exp(s) : 0 into LDS; zs partial ----
    float zs[2] = {0.f, 0.f};
#pragma unroll
    for (int r = 0; r < 2; r++) {
        const int4   a  = ((const int4*)  adj)[(size_t)(i0 + r) * (NNODES/4) + tid];
        const float4 sv = ((const float4*)s  )[(size_t)(i0 + r) * (NNODES/4) + tid];
        float4 e4;
        e4.x = a.x ? __expf(sv.x) : 0.f;
        e4.y = a.y ? __expf(sv.y) : 0.f;
        e4.z = a.z ? __expf(sv.z) : 0.f;
        e4.w = a.w ? __expf(sv.w) : 0.f;
        ((float4*)evL[r])[tid] = e4;
        zs[r] += e4.x + e4.y + e4.z + e4.w;
    }
    const float sH[2] = { srcv[(size_t)i0 * NHEADS + h],
                          srcv[(size_t)(i0 + 1) * NHEADS + h] };
    __syncthreads();

    // ---- Phase A2: ze[r][h] = sum over unmasked j of exp(lrelu(src+dst)) ----
    float ze[2] = {0.f, 0.f};
#pragma unroll 4
    for (int t = 0; t < 32; t++) {
        const int j = t * 32 + js;
        const float d = dstv[j * NHEADS + h];
#pragma unroll
        for (int r = 0; r < 2; r++) {
            float e = sH[r] + d;
            e = e > 0.f ? e : NEG_SLOPE * e;
            const float x = __expf(e);
            ze[r] += (evL[r][j] != 0.f) ? x : 0.f;
        }
    }
#pragma unroll
    for (int off = 8; off <= 32; off <<= 1)
#pragma unroll
        for (int r = 0; r < 2; r++) ze[r] += __shfl_xor(ze[r], off, 64);
#pragma unroll
    for (int off = 1; off <= 32; off <<= 1)
#pragma unroll
        for (int r = 0; r < 2; r++) zs[r] += __shfl_xor(zs[r], off, 64);
    if (lane < NHEADS) { zeA[wv][lane][0] = ze[0]; zeA[wv][lane][1] = ze[1]; }
    if (lane == 0)     { zsA[wv][0] = zs[0]; zsA[wv][1] = zs[1]; }
    __syncthreads();
    if (tid < 16) {
        const int hh = tid & 7, rr = tid >> 3;
        statE[rr][hh] = 1.f / (zeA[0][hh][rr] + zeA[1][hh][rr] +
                               zeA[2][hh][rr] + zeA[3][hh][rr]);
    } else if (tid < 18) {
        const int rr = tid - 16;
        statS[rr] = 1.f / (zsA[0][rr] + zsA[1][rr] + zsA[2][rr] + zsA[3][rr]);
    }
    __syncthreads();
    const float ize[2] = { statE[0][h], statE[1][h] };
    const float izs[2] = { statS[0],    statS[1]    };

    // ---- Phase B: w private, FMA g rows into registers; 1-ahead prefetch ----
    float acc[2][16];
#pragma unroll
    for (int r = 0; r < 2; r++)
#pragma unroll
        for (int f = 0; f < 16; f++) acc[r][f] = 0.f;
    float zt[2] = {0.f, 0.f};

    // preload t = 0
    float  d_c  = dstv[js * NHEADS + h];
    const float4* gj0 = (const float4*)(g + (size_t)js * DIM + h * NHID);
    float4 c0 = gj0[0], c1 = gj0[1], c2 = gj0[2], c3 = gj0[3];
    float  e0_c = evL[0][js], e1_c = evL[1][js];

#pragma unroll 2
    for (int t = 0; t < 32; t++) {
        // prefetch t+1 (dead on last iteration)
        float d_n = 0.f, e0_n = 0.f, e1_n = 0.f;
        float4 n0 = c0, n1 = c1, n2 = c2, n3 = c3;
        if (t < 31) {
            const int jn = (t + 1) * 32 + js;
            d_n = dstv[jn * NHEADS + h];
            const float4* gn = (const float4*)(g + (size_t)jn * DIM + h * NHID);
            n0 = gn[0]; n1 = gn[1]; n2 = gn[2]; n3 = gn[3];
            e0_n = evL[0][jn]; e1_n = evL[1][jn];
        }
        const float evr[2] = { e0_c, e1_c };
#pragma unroll
        for (int r = 0; r < 2; r++) {
            const float ev = evr[r];
            float e = sH[r] + d_c;
            e = e > 0.f ? e : NEG_SLOPE * e;
            const float x   = __expf(e);
            const float arg = (ev != 0.f) ? fmaf(x, ize[r], ev * izs[r]) : 0.f;
            const float w   = __expf(arg);        // exp(0)=1 at masked positions
            zt[r] += w;
            acc[r][0]  = fmaf(w, c0.x, acc[r][0]);
            acc[r][1]  = fmaf(w, c0.y, acc[r][1]);
            acc[r][2]  = fmaf(w, c0.z, acc[r][2]);
            acc[r][3]  = fmaf(w, c0.w, acc[r][3]);
            acc[r][4]  = fmaf(w, c1.x, acc[r][4]);
            acc[r][5]  = fmaf(w, c1.y, acc[r][5]);
            acc[r][6]  = fmaf(w, c1.z, acc[r][6]);
            acc[r][7]  = fmaf(w, c1.w, acc[r][7]);
            acc[r][8]  = fmaf(w, c2.x, acc[r][8]);
            acc[r][9]  = fmaf(w, c2.y, acc[r][9]);
            acc[r][10] = fmaf(w, c2.z, acc[r][10]);
            acc[r][11] = fmaf(w, c2.w, acc[r][11]);
            acc[r][12] = fmaf(w, c3.x, acc[r][12]);
            acc[r][13] = fmaf(w, c3.y, acc[r][13]);
            acc[r][14] = fmaf(w, c3.z, acc[r][14]);
            acc[r][15] = fmaf(w, c3.w, acc[r][15]);
        }
        // rotate
        d_c = d_n; c0 = n0; c1 = n1; c2 = n2; c3 = n3; e0_c = e0_n; e1_c = e1_n;
    }

    // ---- Epilogue: reduce over js-in-wave (lane bits 3..5), then 4 waves ----
#pragma unroll
    for (int off = 8; off <= 32; off <<= 1)
#pragma unroll
        for (int r = 0; r < 2; r++) {
#pragma unroll
            for (int f = 0; f < 16; f++)
                acc[r][f] += __shfl_xor(acc[r][f], off, 64);
            zt[r] += __shfl_xor(zt[r], off, 64);
        }
    if (lane < NHEADS) {
#pragma unroll
        for (int r = 0; r < 2; r++) {
#pragma unroll
            for (int f = 0; f < 16; f++) redO[wv][r][lane][f] = acc[r][f];
            ztA[wv][r][lane] = zt[r];
        }
    }
    __syncthreads();
    {
        const int rr = tid >> 7;
        const int hf = tid & 127;
        const int oh = hf >> 4;
        const int f  = hf & 15;
        const float v  = redO[0][rr][oh][f] + redO[1][rr][oh][f] +
                         redO[2][rr][oh][f] + redO[3][rr][oh][f];
        const float zq = ztA[0][rr][oh] + ztA[1][rr][oh] +
                         ztA[2][rr][oh] + ztA[3][rr][oh];
        out[(size_t)(i0 + rr) * DIM + hf] = v / zq;
    }
}

extern "C" void kernel_launch(void* const* d_in, const int* in_sizes, int n_in,
                              void* d_out, int out_size, void* d_ws, size_t ws_size,
                              hipStream_t stream) {
    const float* h      = (const float*)d_in[0];
    const int*   adj    = (const int*)  d_in[1];
    const float* s      = (const float*)d_in[2];
    const float* W      = (const float*)d_in[3];
    const float* attn_w = (const float*)d_in[4];
    float* out = (float*)d_out;

    float* g    = (float*)d_ws;                      // 1024*128
    float* srcv = g    + (size_t)NNODES * DIM;       // 1024*8
    float* dstv = srcv + (size_t)NNODES * NHEADS;    // 1024*8

    proj_kernel <<<NNODES, DIM, 0, stream>>>(h, W, attn_w, g, srcv, dstv);
    fused_kernel<<<NNODES / 2, 256, 0, stream>>>(adj, s, g, srcv, dstv, out);
}